// Round 5
// baseline (291.799 us; speedup 1.0000x reference)
//
#include <hip/hip_runtime.h>
#include <math.h>

// KoLeo loss: dist_i = sqrt(2 - 2*max_{j!=i} <fhat_i, fhat_j>); loss = -mean(log(dist+1e-8))
// R14 = R13 (verified: 256^2 tile, 16 waves of 64x64, 128 KiB LDS dbuf,
// counted vmcnt staging) + in-tile counted-lgkmcnt pipeline.
// Model (fits R9/R10/R12/R13): one 16x16x128 MFMA = 34.6 cy/SIMD; per K-tile
// per CU: MFMA 2214 cy, LDS reads 2050-3070 cy; all prior structures issue all
// 16 frag-reads at the acquire barrier -> {LDS burst ; MFMA burst} serialize
// -> K-tile 7200 cy -> MfmaUtil == 2214/7200 == 30% in every variant.
// Fix: pipeline reads vs MFMA groups inside the tile with counted lgkmcnt
// (FIFO DS returns), B-frags ping-pong through 2 regs to hold the 128-reg
// (4 waves/SIMD) boundary:
//   issue A0-3,B0,B1 ; lgkm(2) -> ni=0 MFMAs ; issue B2 ; lgkm(2) -> ni=1 ;
//   issue B3 ; lgkm(2) -> ni=2 ; lgkm(0) -> ni=3 ; release barrier.
// First MFMA waits on 10/16 reads; 6 reads hide under the MFMA stream.
// sched_barrier(0) after every counted wait (rule #18). 2 barriers/K-tile.
// 16B-granule XOR swizzle, linear gload_lds dest + pre-swizzled source
// (rule #21). Features pre-scaled x16 before e4m3 cast; raw dots carry x256,
// folded out in row_reduce (max is monotone). Each tile yields row+col max.

#define N_ROWS 16384
#define DIM 1024
#define BT 256
#define BKB 128                   // K bytes per tile (one K=128 MFMA)
#define NKT (DIM / BKB)           // 8
#define NT (N_ROWS / BT)          // 64
#define NBLK (NT * (NT + 1) / 2)  // 2080 (divisible by 8 -> XCD swizzle)

typedef int   i32x4 __attribute__((ext_vector_type(4)));
typedef int   i32x8 __attribute__((ext_vector_type(8)));
typedef float f32x4 __attribute__((ext_vector_type(4)));

__device__ __forceinline__ void async16(const void* g, void* l) {
  __builtin_amdgcn_global_load_lds(
      (__attribute__((address_space(1))) const void*)g,
      (__attribute__((address_space(3))) void*)l, 16, 0, 0);
}

// Raw barrier with compile-time motion fences (rule #18).
#define S_BAR()                        \
  do {                                 \
    __builtin_amdgcn_sched_barrier(0); \
    __builtin_amdgcn_s_barrier();      \
    __builtin_amdgcn_sched_barrier(0); \
  } while (0)
#define WAIT_VM(N) asm volatile("s_waitcnt vmcnt(" #N ")" ::: "memory")
#define WAIT_LGKM_N(N)                                      \
  do {                                                      \
    asm volatile("s_waitcnt lgkmcnt(" #N ")" ::: "memory"); \
    __builtin_amdgcn_sched_barrier(0);                      \
  } while (0)

// ---------------------------------------------------------------- normalize
__global__ __launch_bounds__(256) void normalize_kernel(
    const float* __restrict__ in, unsigned int* __restrict__ outp) {
  const int row = blockIdx.x;
  const int t = threadIdx.x;  // 256 threads x 4 floats
  const float4 v = ((const float4*)(in + (size_t)row * DIM))[t];
  float ss = v.x * v.x + v.y * v.y + v.z * v.z + v.w * v.w;
#pragma unroll
  for (int s = 1; s < 64; s <<= 1) ss += __shfl_xor(ss, s, 64);
  __shared__ float wsum[4];
  const int wave = t >> 6, lane = t & 63;
  if (lane == 0) wsum[wave] = ss;
  __syncthreads();
  const float tot = wsum[0] + wsum[1] + wsum[2] + wsum[3];
  const float scale = 16.f / fmaxf(sqrtf(tot), 1e-12f);
  unsigned int p = __builtin_amdgcn_cvt_pk_fp8_f32(v.x * scale, v.y * scale, 0, false);
  p = __builtin_amdgcn_cvt_pk_fp8_f32(v.z * scale, v.w * scale, p, true);
  outp[(size_t)row * (DIM / 4) + t] = p;
}

// lane reads logical granules 2q,2q+1 of its slot; x0 = swizzled byte offset,
// second granule at x0^16 (since (2q+1)^k == (2q^k)^1).
#define READ_FRAG(dst, base, off)                                    \
  do {                                                               \
    i32x4 _lo = *(const i32x4*)((base) + (off) + x0);                \
    i32x4 _hi = *(const i32x4*)((base) + (off) + (x0 ^ 16));         \
    dst = __builtin_shufflevector(_lo, _hi, 0, 1, 2, 3, 4, 5, 6, 7); \
  } while (0)

#define MFMA1(MI, BF, NI)                                              \
  acc[MI][NI] = __builtin_amdgcn_mfma_scale_f32_16x16x128_f8f6f4(      \
      afr[MI], BF, acc[MI][NI], 0, 0, 0, 0x7F7F7F7F, 0, 0x7F7F7F7F)

#define MFMA_GROUP(BF, NI)                 \
  do {                                     \
    __builtin_amdgcn_s_setprio(1);         \
    MFMA1(0, BF, NI);                      \
    MFMA1(1, BF, NI);                      \
    MFMA1(2, BF, NI);                      \
    MFMA1(3, BF, NI);                      \
    __builtin_amdgcn_s_setprio(0);         \
  } while (0)

// stage both panels' next K-slab: 4 gload_lds per wave (2 A + 2 B)
#define STAGE(bi, k0)                                                 \
  do {                                                                \
    _Pragma("unroll") for (int r = 0; r < 2; ++r) {                   \
      async16(FA + (k0) + srcoff[r], &lds[bi][0][dst_u + r * 16384]); \
      async16(FB + (k0) + srcoff[r], &lds[bi][1][dst_u + r * 16384]); \
    }                                                                 \
  } while (0)

// -------------------------------------------------- Gram row/col-max GEMM
__global__ __launch_bounds__(1024, 4) void gemm_rowmax(
    const unsigned char* __restrict__ F, float* __restrict__ partial) {
  // XCD-chunked bijective swizzle (2080 % 8 == 0), then triangular decode
  int bid = blockIdx.x;
  bid = (bid & 7) * (NBLK / 8) + (bid >> 3);
  double disc = (double)(2 * NT + 1) * (2 * NT + 1) - 8.0 * (double)bid;
  int it = (int)(((2 * NT + 1) - sqrt(disc)) * 0.5);
  if (it > NT - 1) it = NT - 1;
  while (it > 0 && it * NT - it * (it - 1) / 2 > bid) --it;
  while ((it + 1) * NT - (it + 1) * it / 2 <= bid) ++it;
  const int jt = it + (bid - (it * NT - it * (it - 1) / 2));

  __shared__ __align__(16) unsigned char lds[2][2][BT * BKB];  // 128 KiB

  const int ibase = it * BT, jbase = jt * BT;
  const int tid = threadIdx.x;
  const int wave = tid >> 6, lane = tid & 63;
  const int wi = wave >> 2, wj = wave & 3;  // 4x4 wave grid, 64x64 each
  const int quad = lane >> 4, r16 = lane & 15;

  const unsigned char* FA = F + (size_t)ibase * DIM;
  const unsigned char* FB = F + (size_t)jbase * DIM;

  // ---- staging addresses: granule flat = r*1024 + tid; slot = flat>>3
  // (row 0..255); logical granule lg = (flat&7)^(slot&7) -- constant per
  // thread since 1024 % 8 == 0. Per-thread src offset affine in r.
  const unsigned int lg16 = (unsigned int)(((tid & 7) ^ ((tid >> 3) & 7)) << 4);
  unsigned int srcoff[2];
  srcoff[0] = (unsigned int)(tid >> 3) * 1024u + lg16;
  srcoff[1] = srcoff[0] + 131072u;  // +128 rows
  const unsigned int dst_u = (unsigned int)(tid & ~63) * 16u;

  // ---- fragment read offsets (loop-invariant)
  const int x0 = ((2 * quad) ^ (r16 & 7)) << 4;
  const unsigned int a_rd = (unsigned int)(wi * 64 + r16) * BKB;  // + mi*2048
  const unsigned int b_rd = (unsigned int)(wj * 64 + r16) * BKB;  // + ni*2048

  f32x4 acc[4][4] = {};  // [mi][ni] 16x16 tiles (AGPR-resident)
  i32x8 afr[4], bf0, bf1;

  STAGE(0, 0);  // prologue: 4 loads in flight

#pragma unroll 1
  for (int kt = 0; kt < NKT; ++kt) {
    const int cur = kt & 1;
    if (kt < NKT - 1) {
      STAGE(cur ^ 1, (kt + 1) * BKB);  // issue next; 8 in flight
      WAIT_VM(4);                      // previous stage landed (issued 1 iter ago)
    } else {
      WAIT_VM(0);  // epilogue drain
    }
    S_BAR();  // acquire lds[cur]
    const unsigned char* cA = &lds[cur][0][0];
    const unsigned char* cB = &lds[cur][1][0];

    // in-tile counted-lgkm pipeline (FIFO DS returns; each READ_FRAG = 2 ops)
    READ_FRAG(afr[0], cA, a_rd);
    READ_FRAG(afr[1], cA, a_rd + 2048);
    READ_FRAG(afr[2], cA, a_rd + 4096);
    READ_FRAG(afr[3], cA, a_rd + 6144);
    READ_FRAG(bf0, cB, b_rd);          // B0
    READ_FRAG(bf1, cB, b_rd + 2048);   // B1
    WAIT_LGKM_N(2);                    // 12 issued, 10 done: A0-3 + B0
    MFMA_GROUP(bf0, 0);
    READ_FRAG(bf0, cB, b_rd + 4096);   // B2 (WAR on bf0: compiler-ordered)
    WAIT_LGKM_N(2);                    // 14 issued, 12 done: B1
    MFMA_GROUP(bf1, 1);
    READ_FRAG(bf1, cB, b_rd + 6144);   // B3
    WAIT_LGKM_N(2);                    // 16 issued, 14 done: B2
    MFMA_GROUP(bf0, 2);
    WAIT_LGKM_N(0);                    // B3
    MFMA_GROUP(bf1, 3);
    S_BAR();  // release lds[cur] (all reads drained by lgkm(0) above)
  }

  // ---------------- epilogue: row/col max (alias dead staging LDS --
  // lds[0] last read at kt=6, guarded by that iteration's end barrier)
  float(*red)[4] = (float(*)[4]) & lds[0][0][0];           // [256][4] over wj
  float(*redc)[4] = (float(*)[4])(&lds[0][0][0] + 4096);   // [256][4] over wi

  // C/D layout (16x16): col = lane&15, row = quad*4 + reg.
#pragma unroll
  for (int mi = 0; mi < 4; ++mi) {
#pragma unroll
    for (int r = 0; r < 4; ++r) {
      const int rl = wi * 64 + mi * 16 + quad * 4 + r;
      const int rowg = ibase + rl;
      float m = -INFINITY;
#pragma unroll
      for (int ni = 0; ni < 4; ++ni) {
        const int colg = jbase + wj * 64 + ni * 16 + r16;
        const float v = acc[mi][ni][r];
        m = (rowg == colg) ? m : fmaxf(m, v);
      }
#pragma unroll
      for (int s = 1; s < 16; s <<= 1) m = fmaxf(m, __shfl_xor(m, s, 64));
      if (r16 == 0) red[rl][wj] = m;
    }
  }
  if (it != jt) {  // col-max (off-diagonal tiles: no diag elements present)
#pragma unroll
    for (int ni = 0; ni < 4; ++ni) {
      float m = -INFINITY;
#pragma unroll
      for (int mi = 0; mi < 4; ++mi)
#pragma unroll
        for (int r = 0; r < 4; ++r) m = fmaxf(m, acc[mi][ni][r]);
      m = fmaxf(m, __shfl_xor(m, 16, 64));  // reduce across quads
      m = fmaxf(m, __shfl_xor(m, 32, 64));
      if (quad == 0) redc[wj * 64 + ni * 16 + r16][wi] = m;
    }
  }
  __syncthreads();
  if (tid < BT) {
    const float a = fmaxf(red[tid][0], red[tid][1]);
    const float b = fmaxf(red[tid][2], red[tid][3]);
    partial[(size_t)jt * N_ROWS + ibase + tid] = fmaxf(a, b);
  } else if (tid < 2 * BT && it != jt) {
    const int c = tid - BT;
    const float a = fmaxf(redc[c][0], redc[c][1]);
    const float b = fmaxf(redc[c][2], redc[c][3]);
    partial[(size_t)it * N_ROWS + jbase + c] = fmaxf(a, b);
  }
}

// ------------------------------------------------------------- reductions
__global__ __launch_bounds__(256) void row_reduce(
    const float* __restrict__ partial, float* __restrict__ blocksum) {
  const int r = blockIdx.x * 256 + threadIdx.x;
  float m = -INFINITY;
  for (int p = 0; p < NT; ++p)
    m = fmaxf(m, partial[(size_t)p * N_ROWS + r]);
  // raw dot carries x256 (features scaled x16): 2 - 2*(m/256) = 2 - m/128
  const float d2 = fmaxf(2.f - m * (1.f / 128.f), 0.f);
  float term = logf(sqrtf(d2) + 1e-8f);
#pragma unroll
  for (int s = 1; s < 64; s <<= 1) term += __shfl_xor(term, s, 64);
  __shared__ float wsum[4];
  const int wave = threadIdx.x >> 6, lane = threadIdx.x & 63;
  if (lane == 0) wsum[wave] = term;
  __syncthreads();
  if (threadIdx.x == 0)
    blocksum[blockIdx.x] = wsum[0] + wsum[1] + wsum[2] + wsum[3];
}

__global__ void finalize(const float* __restrict__ blocksum,
                         float* __restrict__ out) {
  float v = blocksum[threadIdx.x];
#pragma unroll
  for (int s = 1; s < 64; s <<= 1) v += __shfl_xor(v, s, 64);
  if (threadIdx.x == 0) out[0] = -v / (float)N_ROWS;
}

// ---------------------------------------------------------------- launcher
extern "C" void kernel_launch(void* const* d_in, const int* in_sizes, int n_in,
                              void* d_out, int out_size, void* d_ws, size_t ws_size,
                              hipStream_t stream) {
  const float* feats = (const float*)d_in[0];
  float* out = (float*)d_out;
  char* ws = (char*)d_ws;

  // ws: [0,16MB) fp8 features; [16MB,20MB) partial [64][16384] f32; then sums.
  unsigned char* f8 = (unsigned char*)ws;
  float* partial = (float*)(ws + (size_t)N_ROWS * DIM);
  float* blocksum =
      (float*)(ws + (size_t)N_ROWS * DIM + (size_t)NT * N_ROWS * 4);

  normalize_kernel<<<N_ROWS, 256, 0, stream>>>(feats, (unsigned int*)f8);
  gemm_rowmax<<<NBLK, 1024, 0, stream>>>(f8, partial);
  row_reduce<<<N_ROWS / 256, 256, 0, stream>>>(partial, blocksum);
  finalize<<<1, 64, 0, stream>>>(blocksum, out);
}

// Round 6
// 286.395 us; speedup vs baseline: 1.0189x; 1.0189x over previous
//
#include <hip/hip_runtime.h>
#include <math.h>

// KoLeo loss: dist_i = sqrt(2 - 2*max_{j!=i} <fhat_i, fhat_j>); loss = -mean(log(dist+1e-8))
// R15: 256^2 tile, 8 waves of 128x64 (2x4 grid), 512 threads, 128 KiB LDS
// dbuf, ONE barrier per K-tile, in-wave read/MFMA pipeline.
// Model (fits R9-R14): dur x MfmaUtil == 59 us MFMA floor in every structure;
// the wall is the per-tile {LDS read burst ; MFMA burst} serialization (LDS
// round-robin sync-izes read completion across waves). R14's fix was right
// but spilled (WRITE_SIZE 4->61 MB: +8 VGPR past the 128-reg cap at 4w/SIMD).
// 128x64 waves give the headroom: 2 waves/SIMD -> 256-reg budget; acc 128 +
// afr 64 + bfr 32 + addr ~20 = ~245. Reads/tile drop 256->192 b128
// (redundancy 4x->3x): read-pipe ~2300 cy <= MFMA 2208 cy/SIMD -> hideable.
// Per tile: lgkm0 (release, end of prev) ; vmcnt(0) [cur stage, issued a full
// tile ago -> instant, no younger loads] ; s_barrier ; STAGE(next) [post-
// barrier => prev buffer provably drained by all waves] ; issue all 24
// ds_reads order-pinned (sched_barrier(0) between each) ; 8 MFMA groups in
// order -- hipcc inserts minimal counted lgkm per group (order is pinned);
// group0 waits on 10/24 reads, the rest hide under 1104 cy of MFMA.
// 16B-granule XOR swizzle, linear gload_lds dest + pre-swizzled source
// (rule #21). Features pre-scaled x16 before e4m3 cast; raw dots carry x256,
// folded out in row_reduce (max is monotone). Each tile yields row+col max.

#define N_ROWS 16384
#define DIM 1024
#define BT 256
#define BKB 128                   // K bytes per tile (one K=128 MFMA)
#define NKT (DIM / BKB)           // 8
#define NT (N_ROWS / BT)          // 64
#define NBLK (NT * (NT + 1) / 2)  // 2080 (divisible by 8 -> XCD swizzle)

typedef int   i32x4 __attribute__((ext_vector_type(4)));
typedef int   i32x8 __attribute__((ext_vector_type(8)));
typedef float f32x4 __attribute__((ext_vector_type(4)));

__device__ __forceinline__ void async16(const void* g, void* l) {
  __builtin_amdgcn_global_load_lds(
      (__attribute__((address_space(1))) const void*)g,
      (__attribute__((address_space(3))) void*)l, 16, 0, 0);
}

#define SB0 __builtin_amdgcn_sched_barrier(0)
#define S_BAR()                   \
  do {                            \
    SB0;                          \
    __builtin_amdgcn_s_barrier(); \
    SB0;                          \
  } while (0)
#define WAIT_VM(N) asm volatile("s_waitcnt vmcnt(" #N ")" ::: "memory")
#define WAIT_LGKM0()                                   \
  do {                                                 \
    asm volatile("s_waitcnt lgkmcnt(0)" ::: "memory"); \
    SB0;                                               \
  } while (0)

// ---------------------------------------------------------------- normalize
__global__ __launch_bounds__(256) void normalize_kernel(
    const float* __restrict__ in, unsigned int* __restrict__ outp) {
  const int row = blockIdx.x;
  const int t = threadIdx.x;  // 256 threads x 4 floats
  const float4 v = ((const float4*)(in + (size_t)row * DIM))[t];
  float ss = v.x * v.x + v.y * v.y + v.z * v.z + v.w * v.w;
#pragma unroll
  for (int s = 1; s < 64; s <<= 1) ss += __shfl_xor(ss, s, 64);
  __shared__ float wsum[4];
  const int wave = t >> 6, lane = t & 63;
  if (lane == 0) wsum[wave] = ss;
  __syncthreads();
  const float tot = wsum[0] + wsum[1] + wsum[2] + wsum[3];
  const float scale = 16.f / fmaxf(sqrtf(tot), 1e-12f);
  unsigned int p = __builtin_amdgcn_cvt_pk_fp8_f32(v.x * scale, v.y * scale, 0, false);
  p = __builtin_amdgcn_cvt_pk_fp8_f32(v.z * scale, v.w * scale, p, true);
  outp[(size_t)row * (DIM / 4) + t] = p;
}

// lane reads logical granules 2q,2q+1 of its slot; x0 = swizzled byte offset,
// second granule at x0^16 (since (2q+1)^k == (2q^k)^1).
#define READ_FRAG(dst, base, off)                                    \
  do {                                                               \
    i32x4 _lo = *(const i32x4*)((base) + (off) + x0);                \
    i32x4 _hi = *(const i32x4*)((base) + (off) + (x0 ^ 16));         \
    dst = __builtin_shufflevector(_lo, _hi, 0, 1, 2, 3, 4, 5, 6, 7); \
  } while (0)

#define MFMA1(MI, NI)                                             \
  acc[MI][NI] = __builtin_amdgcn_mfma_scale_f32_16x16x128_f8f6f4( \
      afr[MI], bfr[NI], acc[MI][NI], 0, 0, 0, 0x7F7F7F7F, 0, 0x7F7F7F7F)

#define GROUP(MI)                  \
  do {                             \
    __builtin_amdgcn_s_setprio(1); \
    MFMA1(MI, 0);                  \
    MFMA1(MI, 1);                  \
    MFMA1(MI, 2);                  \
    MFMA1(MI, 3);                  \
    __builtin_amdgcn_s_setprio(0); \
    SB0;                           \
  } while (0)

// stage both panels' next K-slab: 8 gload_lds per thread (512 thr x 16 B x 4
// rounds = 32 KiB per panel)
#define STAGE(bi, k0)                                                      \
  do {                                                                     \
    _Pragma("unroll") for (int r = 0; r < 4; ++r) {                        \
      async16(FA + (k0) + sa0 + r * 65536, &lds[bi][0][dst_u + r * 8192]); \
      async16(FB + (k0) + sa0 + r * 65536, &lds[bi][1][dst_u + r * 8192]); \
    }                                                                      \
  } while (0)

// -------------------------------------------------- Gram row/col-max GEMM
__global__ __launch_bounds__(512, 2) void gemm_rowmax(
    const unsigned char* __restrict__ F, float* __restrict__ partial) {
  // XCD-chunked bijective swizzle (2080 % 8 == 0), then triangular decode
  int bid = blockIdx.x;
  bid = (bid & 7) * (NBLK / 8) + (bid >> 3);
  double disc = (double)(2 * NT + 1) * (2 * NT + 1) - 8.0 * (double)bid;
  int it = (int)(((2 * NT + 1) - sqrt(disc)) * 0.5);
  if (it > NT - 1) it = NT - 1;
  while (it > 0 && it * NT - it * (it - 1) / 2 > bid) --it;
  while ((it + 1) * NT - (it + 1) * it / 2 <= bid) ++it;
  const int jt = it + (bid - (it * NT - it * (it - 1) / 2));

  __shared__ __align__(16) unsigned char lds[2][2][BT * BKB];  // 128 KiB

  const int ibase = it * BT, jbase = jt * BT;
  const int tid = threadIdx.x;
  const int wave = tid >> 6, lane = tid & 63;
  const int wi = wave >> 2, wj = wave & 3;  // 2x4 wave grid, 128x64 each
  const int quad = lane >> 4, r16 = lane & 15;

  const unsigned char* FA = F + (size_t)ibase * DIM;
  const unsigned char* FB = F + (size_t)jbase * DIM;

  // ---- staging addresses: round r granule flat = r*512 + tid; slot =
  // flat>>3 = r*64 + (tid>>3); lg = (tid&7)^((tid>>3)&7) (const: 64%8==0).
  const unsigned int lg16 = (unsigned int)(((tid & 7) ^ ((tid >> 3) & 7)) << 4);
  const unsigned int sa0 = (unsigned int)(tid >> 3) * 1024u + lg16;
  const unsigned int dst_u = (unsigned int)(tid & ~63) * 16u;

  // ---- fragment read offsets (loop-invariant)
  const int x0 = ((2 * quad) ^ (r16 & 7)) << 4;
  const unsigned int a_rd = (unsigned int)(wi * 128 + r16) * BKB;  // + mi*2048
  const unsigned int b_rd = (unsigned int)(wj * 64 + r16) * BKB;   // + ni*2048

  f32x4 acc[8][4] = {};  // [mi][ni] 16x16 tiles (AGPR-resident, 128 regs)
  i32x8 afr[8], bfr[4];

  STAGE(0, 0);  // prologue: 8 loads in flight

#pragma unroll 1
  for (int kt = 0; kt < NKT; ++kt) {
    const int cur = kt & 1;
    WAIT_VM(0);  // cur's stage (issued a full tile ago; instant after kt=0)
    S_BAR();     // all waves: cur staged + prev buffer's reads drained
    if (kt < NKT - 1) STAGE(cur ^ 1, (kt + 1) * BKB);  // post-barrier: safe
    const unsigned char* cA = &lds[cur][0][0];
    const unsigned char* cB = &lds[cur][1][0];

    // issue all 24 ds_reads, order-pinned; compiler inserts counted lgkm
    // before each group's first MFMA (FIFO DS returns)
    READ_FRAG(bfr[0], cB, b_rd);          SB0;
    READ_FRAG(bfr[1], cB, b_rd + 2048);   SB0;
    READ_FRAG(bfr[2], cB, b_rd + 4096);   SB0;
    READ_FRAG(bfr[3], cB, b_rd + 6144);   SB0;
    READ_FRAG(afr[0], cA, a_rd);          SB0;
    READ_FRAG(afr[1], cA, a_rd + 2048);   SB0;
    READ_FRAG(afr[2], cA, a_rd + 4096);   SB0;
    READ_FRAG(afr[3], cA, a_rd + 6144);   SB0;
    READ_FRAG(afr[4], cA, a_rd + 8192);   SB0;
    READ_FRAG(afr[5], cA, a_rd + 10240);  SB0;
    READ_FRAG(afr[6], cA, a_rd + 12288);  SB0;
    READ_FRAG(afr[7], cA, a_rd + 14336);  SB0;
    GROUP(0);
    GROUP(1);
    GROUP(2);
    GROUP(3);
    GROUP(4);
    GROUP(5);
    GROUP(6);
    GROUP(7);
    WAIT_LGKM0();  // release: my reads of cur drained before next barrier
  }

  // ---------------- epilogue: row/col max (alias dead staging LDS)
  __syncthreads();
  float(*red)[4] = (float(*)[4]) & lds[0][0][0];          // [256][4] over wj
  float(*redc)[2] = (float(*)[2])(&lds[0][0][0] + 4096);  // [256][2] over wi

  // C/D layout (16x16): col = lane&15, row = quad*4 + reg.
#pragma unroll
  for (int mi = 0; mi < 8; ++mi) {
#pragma unroll
    for (int r = 0; r < 4; ++r) {
      const int rl = wi * 128 + mi * 16 + quad * 4 + r;
      const int rowg = ibase + rl;
      float m = -INFINITY;
#pragma unroll
      for (int ni = 0; ni < 4; ++ni) {
        const int colg = jbase + wj * 64 + ni * 16 + r16;
        const float v = acc[mi][ni][r];
        m = (rowg == colg) ? m : fmaxf(m, v);
      }
#pragma unroll
      for (int s = 1; s < 16; s <<= 1) m = fmaxf(m, __shfl_xor(m, s, 64));
      if (r16 == 0) red[rl][wj] = m;
    }
  }
  if (it != jt) {  // col-max (off-diagonal tiles: no diag elements present)
#pragma unroll
    for (int ni = 0; ni < 4; ++ni) {
      float m = -INFINITY;
#pragma unroll
      for (int mi = 0; mi < 8; ++mi)
#pragma unroll
        for (int r = 0; r < 4; ++r) m = fmaxf(m, acc[mi][ni][r]);
      m = fmaxf(m, __shfl_xor(m, 16, 64));  // reduce across quads
      m = fmaxf(m, __shfl_xor(m, 32, 64));
      if (quad == 0) redc[wj * 64 + ni * 16 + r16][wi] = m;
    }
  }
  __syncthreads();
  if (tid < BT) {
    const float a = fmaxf(red[tid][0], red[tid][1]);
    const float b = fmaxf(red[tid][2], red[tid][3]);
    partial[(size_t)jt * N_ROWS + ibase + tid] = fmaxf(a, b);
  } else if (it != jt) {
    const int c = tid - BT;
    partial[(size_t)it * N_ROWS + jbase + c] = fmaxf(redc[c][0], redc[c][1]);
  }
}

// ------------------------------------------------------------- reductions
__global__ __launch_bounds__(256) void row_reduce(
    const float* __restrict__ partial, float* __restrict__ blocksum) {
  const int r = blockIdx.x * 256 + threadIdx.x;
  float m = -INFINITY;
  for (int p = 0; p < NT; ++p)
    m = fmaxf(m, partial[(size_t)p * N_ROWS + r]);
  // raw dot carries x256 (features scaled x16): 2 - 2*(m/256) = 2 - m/128
  const float d2 = fmaxf(2.f - m * (1.f / 128.f), 0.f);
  float term = logf(sqrtf(d2) + 1e-8f);
#pragma unroll
  for (int s = 1; s < 64; s <<= 1) term += __shfl_xor(term, s, 64);
  __shared__ float wsum[4];
  const int wave = threadIdx.x >> 6, lane = threadIdx.x & 63;
  if (lane == 0) wsum[wave] = term;
  __syncthreads();
  if (threadIdx.x == 0)
    blocksum[blockIdx.x] = wsum[0] + wsum[1] + wsum[2] + wsum[3];
}

__global__ void finalize(const float* __restrict__ blocksum,
                         float* __restrict__ out) {
  float v = blocksum[threadIdx.x];
#pragma unroll
  for (int s = 1; s < 64; s <<= 1) v += __shfl_xor(v, s, 64);
  if (threadIdx.x == 0) out[0] = -v / (float)N_ROWS;
}

// ---------------------------------------------------------------- launcher
extern "C" void kernel_launch(void* const* d_in, const int* in_sizes, int n_in,
                              void* d_out, int out_size, void* d_ws, size_t ws_size,
                              hipStream_t stream) {
  const float* feats = (const float*)d_in[0];
  float* out = (float*)d_out;
  char* ws = (char*)d_ws;

  // ws: [0,16MB) fp8 features; [16MB,20MB) partial [64][16384] f32; then sums.
  unsigned char* f8 = (unsigned char*)ws;
  float* partial = (float*)(ws + (size_t)N_ROWS * DIM);
  float* blocksum =
      (float*)(ws + (size_t)N_ROWS * DIM + (size_t)NT * N_ROWS * 4);

  normalize_kernel<<<N_ROWS, 256, 0, stream>>>(feats, (unsigned int*)f8);
  gemm_rowmax<<<NBLK, 512, 0, stream>>>(f8, partial);
  row_reduce<<<N_ROWS / 256, 256, 0, stream>>>(partial, blocksum);
  finalize<<<1, 64, 0, stream>>>(blocksum, out);
}